// Round 5
// baseline (605.506 us; speedup 1.0000x reference)
//
#include <hip/hip_runtime.h>
#include <hip/hip_bf16.h>
#include <hip/hip_fp16.h>

#define NEG_SLOPE 0.2f

__device__ __forceinline__ float leaky(float a) { return a > 0.f ? a : NEG_SLOPE * a; }

// ---------------- wvec: wv[0..15] = We1 @ ae1, wv[16..31] = We2 @ ae2 ----------------
__global__ void compute_wvec(const float* __restrict__ We1, const float* __restrict__ ae1,
                             const float* __restrict__ We2, const float* __restrict__ ae2,
                             float* __restrict__ wv) {
    int t = threadIdx.x;
    if (t < 16) {
        float s = 0.f;
        for (int k = 0; k < 64; ++k) s += We1[t * 64 + k] * ae1[k];
        wv[t] = s;
    } else if (t < 32) {
        int f = t - 16;
        float s = 0.f;
        for (int k = 0; k < 64; ++k) s += We2[f * 64 + k] * ae2[k];
        wv[16 + f] = s;
    }
}

// ---------------- pack: dense payload (ea1:f16 | ea2:f16<<16) + degree count ----------------
__global__ void pack_edges(const int* __restrict__ dst, const float* __restrict__ eattr,
                           const float* __restrict__ wv, int* __restrict__ cursor,
                           unsigned int* __restrict__ pay, int E) {
    __shared__ float w1s[16], w2s[16];
    if (threadIdx.x < 16) w1s[threadIdx.x] = wv[threadIdx.x];
    else if (threadIdx.x < 32) w2s[threadIdx.x - 16] = wv[threadIdx.x];
    __syncthreads();
    int e = blockIdx.x * blockDim.x + threadIdx.x;
    if (e >= E) return;
    const float4* ep = (const float4*)(eattr + (size_t)e * 16);
    float4 q0 = ep[0], q1 = ep[1], q2 = ep[2], q3 = ep[3];
    float a[16] = {q0.x, q0.y, q0.z, q0.w, q1.x, q1.y, q1.z, q1.w,
                   q2.x, q2.y, q2.z, q2.w, q3.x, q3.y, q3.z, q3.w};
    float s1 = 0.f, s2 = 0.f;
#pragma unroll
    for (int f = 0; f < 16; ++f) { s1 += a[f] * w1s[f]; s2 += a[f] * w2s[f]; }
    unsigned int p1 = (unsigned int)__half_as_ushort(__float2half_rn(s1));
    unsigned int p2 = (unsigned int)__half_as_ushort(__float2half_rn(s2));
    pay[e] = p1 | (p2 << 16);
    atomicAdd(&cursor[dst[e]], 1);
}

// ---------------- 3-kernel exclusive scan: deg -> rowptr ----------------
__global__ void scan_blocks(const int* __restrict__ deg, int* __restrict__ rowptr,
                            int* __restrict__ bsum, int n) {
    __shared__ int sh[1024];
    int i = blockIdx.x * 1024 + threadIdx.x;
    sh[threadIdx.x] = (i < n) ? deg[i] : 0;
    __syncthreads();
    for (int off = 1; off < 1024; off <<= 1) {
        int t = (threadIdx.x >= off) ? sh[threadIdx.x - off] : 0;
        __syncthreads();
        sh[threadIdx.x] += t;
        __syncthreads();
    }
    if (i < n) rowptr[i + 1] = sh[threadIdx.x];  // inclusive, pre-offset
    if (threadIdx.x == 1023) bsum[blockIdx.x] = sh[1023];
}

__global__ void scan_sums(int* __restrict__ bsum, int nb) {
    if (blockIdx.x == 0 && threadIdx.x == 0) {
        int run = 0;
        for (int b = 0; b < nb; ++b) { int t = bsum[b]; bsum[b] = run; run += t; }
    }
}

__global__ void scan_finalize(int* __restrict__ rowptr, const int* __restrict__ bsum,
                              int* __restrict__ cursor, int n) {
    int i = blockIdx.x * blockDim.x + threadIdx.x;
    if (i < n) {
        int val = rowptr[i + 1] + bsum[i >> 10];
        rowptr[i + 1] = val;
        if (i + 1 < n) cursor[i + 1] = val;
    }
    if (i == 0) { rowptr[0] = 0; cursor[0] = 0; }
}

// ---------------- route: XCD-local CSR scatter ----------------
// Workgroup w handles only dst in slice (w&7); with round-robin blockIdx->XCD
// dispatch, each 1.6MB recs slice is written by a single XCD, so lines stay in
// that L2 and fill up (~8 records/line) before writeback. Correct under ANY
// workgroup->XCD mapping (locality heuristic only).
__global__ __launch_bounds__(256) void route_edges(
    const int* __restrict__ src, const int* __restrict__ dst,
    const unsigned int* __restrict__ pay, int* __restrict__ cursor,
    uint2* __restrict__ recs, int E, int slice_sz) {
    int xcd = blockIdx.x & 7;
    int team = blockIdx.x >> 3;
    int teams = gridDim.x >> 3;
    int lo = xcd * slice_sz, hi = lo + slice_sz;
    for (int e = team * 256 + threadIdx.x; e < E; e += teams * 256) {
        int d = dst[e];
        if (d < lo || d >= hi) continue;
        int pos = atomicAdd(&cursor[d], 1);
        recs[pos] = make_uint2((unsigned int)src[e], pay[e]);
    }
}

// ---------------- node GEMM: h = X@W (K x 64), plus ash = h.a_s, adh = h.a_d ----------------
template <int K>
__global__ __launch_bounds__(256) void gemm_node(const float* __restrict__ X,
                                                 const float* __restrict__ W,
                                                 const float* __restrict__ a_s,
                                                 const float* __restrict__ a_d,
                                                 float* __restrict__ Hout,
                                                 float* __restrict__ ash,
                                                 float* __restrict__ adh, int n) {
    constexpr int KC = 64;
    __shared__ float xs[128 * 65];
    __shared__ float ws[KC * 64];
    int tid = threadIdx.x;
    int base = blockIdx.x * 128;
    int ct = tid & 7;   // cols ct*8 .. ct*8+7
    int rt = tid >> 3;  // rows rt*4 .. rt*4+3

    float acc[4][8];
#pragma unroll
    for (int i = 0; i < 4; ++i)
#pragma unroll
        for (int j = 0; j < 8; ++j) acc[i][j] = 0.f;

    for (int kc = 0; kc < K; kc += KC) {
#pragma unroll
        for (int p = 0; p < 8; ++p) {
            int idx = p * 256 + tid;  // 2048 float4s
            int row = idx >> 4;
            int f4 = idx & 15;
            float4 q = make_float4(0.f, 0.f, 0.f, 0.f);
            if (base + row < n) q = *(const float4*)(X + (size_t)(base + row) * K + kc + f4 * 4);
            float* dp = xs + row * 65 + f4 * 4;
            dp[0] = q.x; dp[1] = q.y; dp[2] = q.z; dp[3] = q.w;
        }
#pragma unroll
        for (int p = 0; p < 4; ++p) {
            int idx = p * 256 + tid;  // 1024 float4s
            int f = idx >> 4;
            int c4 = idx & 15;
            *(float4*)(ws + f * 64 + c4 * 4) =
                *(const float4*)(W + (size_t)(kc + f) * 64 + c4 * 4);
        }
        __syncthreads();
#pragma unroll 4
        for (int f = 0; f < KC; ++f) {
            float4 w0 = *(const float4*)(ws + f * 64 + ct * 8);
            float4 w1 = *(const float4*)(ws + f * 64 + ct * 8 + 4);
            float b0[8] = {w0.x, w0.y, w0.z, w0.w, w1.x, w1.y, w1.z, w1.w};
#pragma unroll
            for (int i = 0; i < 4; ++i) {
                float a = xs[(rt * 4 + i) * 65 + f];
#pragma unroll
                for (int j = 0; j < 8; ++j) acc[i][j] = fmaf(a, b0[j], acc[i][j]);
            }
        }
        __syncthreads();
    }

    float as_r[8], ad_r[8];
#pragma unroll
    for (int j = 0; j < 8; ++j) { as_r[j] = a_s[ct * 8 + j]; ad_r[j] = a_d[ct * 8 + j]; }
#pragma unroll
    for (int i = 0; i < 4; ++i) {
        int r = base + rt * 4 + i;
        float ps = 0.f, pd = 0.f;
#pragma unroll
        for (int j = 0; j < 8; ++j) {
            ps = fmaf(acc[i][j], as_r[j], ps);
            pd = fmaf(acc[i][j], ad_r[j], pd);
        }
        ps += __shfl_xor(ps, 1); pd += __shfl_xor(pd, 1);
        ps += __shfl_xor(ps, 2); pd += __shfl_xor(pd, 2);
        ps += __shfl_xor(ps, 4); pd += __shfl_xor(pd, 4);
        if (r < n) {
            *(float4*)(Hout + (size_t)r * 64 + ct * 8) =
                make_float4(acc[i][0], acc[i][1], acc[i][2], acc[i][3]);
            *(float4*)(Hout + (size_t)r * 64 + ct * 8 + 4) =
                make_float4(acc[i][4], acc[i][5], acc[i][6], acc[i][7]);
            if (ct == 0) { ash[r] = ps; adh[r] = pd; }
        }
    }
}

// ---------------- GAT aggregation: one wave per destination node ----------------
template <int LAYER>
__global__ __launch_bounds__(256) void gat_aggregate(
    const float* __restrict__ Hf, const float* __restrict__ ash, const float* __restrict__ adh,
    const int* __restrict__ rowptr, const uint2* __restrict__ recs,
    const float* __restrict__ bias, float* __restrict__ outp, int n) {
    int wave = threadIdx.x >> 6;
    int lane = threadIdx.x & 63;
    int i = blockIdx.x * 4 + wave;
    if (i >= n) return;
    int start = rowptr[i], end = rowptr[i + 1];
    float adi = adh[i];

    auto gete = [](unsigned int y) -> float {
        unsigned short u = (LAYER == 0) ? (unsigned short)(y & 0xffffu) : (unsigned short)(y >> 16);
        return __half2float(__ushort_as_half(u));
    };

    float acc = 0.f, z = 0.f, sea = 0.f;
    int j = start;
    for (; j + 4 <= end; j += 4) {
        uint2 r0 = recs[j], r1 = recs[j + 1], r2 = recs[j + 2], r3 = recs[j + 3];
        int s0 = (int)r0.x, s1 = (int)r1.x, s2 = (int)r2.x, s3 = (int)r3.x;
        float e0 = gete(r0.y), e1 = gete(r1.y), e2 = gete(r2.y), e3 = gete(r3.y);
        float a0 = ash[s0], a1 = ash[s1], a2 = ash[s2], a3 = ash[s3];
        float v0 = Hf[(size_t)s0 * 64 + lane];
        float v1 = Hf[(size_t)s1 * 64 + lane];
        float v2 = Hf[(size_t)s2 * 64 + lane];
        float v3 = Hf[(size_t)s3 * 64 + lane];
        float p0 = __expf(leaky(a0 + adi + e0));
        float p1 = __expf(leaky(a1 + adi + e1));
        float p2 = __expf(leaky(a2 + adi + e2));
        float p3 = __expf(leaky(a3 + adi + e3));
        acc = fmaf(p0, v0, acc);
        acc = fmaf(p1, v1, acc);
        acc = fmaf(p2, v2, acc);
        acc = fmaf(p3, v3, acc);
        z += (p0 + p1) + (p2 + p3);
        sea += (e0 + e1) + (e2 + e3);
    }
    for (; j < end; ++j) {
        uint2 r = recs[j];
        int s = (int)r.x;
        float e = gete(r.y);
        float v = Hf[(size_t)s * 64 + lane];
        float p = __expf(leaky(ash[s] + adi + e));
        acc = fmaf(p, v, acc);
        z += p;
        sea += e;
    }

    int d = end - start;
    float loop_sc = sea / (float)max(d, 1);
    float aself = leaky(ash[i] + adi + loop_sc);
    float pself = __expf(aself);
    z += pself;
    acc = fmaf(pself, Hf[(size_t)i * 64 + lane], acc);
    float o = acc / z + bias[lane];
    outp[(size_t)i * 64 + lane] = fmaxf(o, 0.f);  // both GAT layers are ReLU'd
}

// ---------------- classifier MLP: relu(X@Wc1+bc1)@Wc2+bc2 ----------------
__global__ __launch_bounds__(256) void mlp_kernel(const float* __restrict__ X,
                                                  const float* __restrict__ Wc1,
                                                  const float* __restrict__ bc1,
                                                  const float* __restrict__ Wc2,
                                                  const float* __restrict__ bc2,
                                                  float* __restrict__ outp, int n) {
    __shared__ float v[8 * 64];
    __shared__ float tb[8 * 32];
    int base = blockIdx.x * 8;
    for (int t = threadIdx.x; t < 512; t += 256) {
        int r = t >> 6;
        v[t] = (base + r < n) ? X[(size_t)base * 64 + t] : 0.f;
    }
    __syncthreads();
    int r = threadIdx.x >> 5, j = threadIdx.x & 31;
    float acc = bc1[j];
#pragma unroll
    for (int k = 0; k < 64; ++k) acc += v[r * 64 + k] * Wc1[k * 32 + j];
    acc = fmaxf(acc, 0.f);
    tb[r * 32 + j] = acc;
    __syncthreads();
    float lg = bc2[j];
#pragma unroll
    for (int k2 = 0; k2 < 32; ++k2) lg += tb[r * 32 + k2] * Wc2[k2 * 32 + j];
    int row = base + r;
    if (row < n) outp[(size_t)row * 32 + j] = lg;
}

extern "C" void kernel_launch(void* const* d_in, const int* in_sizes, int n_in,
                              void* d_out, int out_size, void* d_ws, size_t ws_size,
                              hipStream_t stream) {
    const float* x    = (const float*)d_in[0];
    const int*   ei   = (const int*)d_in[1];
    const float* eatt = (const float*)d_in[2];
    const float* W1   = (const float*)d_in[3];
    const float* as1  = (const float*)d_in[4];
    const float* ad1  = (const float*)d_in[5];
    const float* We1  = (const float*)d_in[6];
    const float* ae1  = (const float*)d_in[7];
    const float* b1   = (const float*)d_in[8];
    const float* W2   = (const float*)d_in[9];
    const float* as2  = (const float*)d_in[10];
    const float* ad2  = (const float*)d_in[11];
    const float* We2  = (const float*)d_in[12];
    const float* ae2  = (const float*)d_in[13];
    const float* b2   = (const float*)d_in[14];
    const float* Wc1  = (const float*)d_in[15];
    const float* bc1  = (const float*)d_in[16];
    const float* Wc2  = (const float*)d_in[17];
    const float* bc2  = (const float*)d_in[18];

    int n = in_sizes[0] / 128;
    int E = in_sizes[1] / 2;
    const int* src = ei;
    const int* dst = ei + E;

    // workspace carve (256B aligned)
    char* w = (char*)d_ws;
    auto alloc = [&](size_t bytes) { void* p = (void*)w; w += (bytes + 255) & ~(size_t)255; return p; };
    int* rowptr  = (int*)alloc((size_t)(n + 1) * 4);
    int* cursor  = (int*)alloc((size_t)n * 4);          // deg, then running cursor
    int nb = (n + 1023) / 1024;
    int* bsum    = (int*)alloc((size_t)nb * 4);
    uint2* recs  = (uint2*)alloc((size_t)E * 8);
    unsigned int* pay = (unsigned int*)alloc((size_t)E * 4);
    float* wv    = (float*)alloc(32 * 4);
    float* hbuf  = (float*)alloc((size_t)n * 64 * 4);
    float* obuf  = (float*)alloc((size_t)n * 64 * 4);
    float* ash   = (float*)alloc((size_t)n * 4);
    float* adh   = (float*)alloc((size_t)n * 4);

    int slice_sz = (n + 7) / 8;

    hipMemsetAsync(cursor, 0, (size_t)n * 4, stream);
    compute_wvec<<<1, 64, 0, stream>>>(We1, ae1, We2, ae2, wv);
    pack_edges<<<(E + 255) / 256, 256, 0, stream>>>(dst, eatt, wv, cursor, pay, E);
    scan_blocks<<<nb, 1024, 0, stream>>>(cursor, rowptr, bsum, n);
    scan_sums<<<1, 64, 0, stream>>>(bsum, nb);
    scan_finalize<<<(n + 255) / 256, 256, 0, stream>>>(rowptr, bsum, cursor, n);
    route_edges<<<1024, 256, 0, stream>>>(src, dst, pay, cursor, recs, E, slice_sz);

    // layer 1
    gemm_node<128><<<(n + 127) / 128, 256, 0, stream>>>(x, W1, as1, ad1, hbuf, ash, adh, n);
    gat_aggregate<0><<<(n + 3) / 4, 256, 0, stream>>>(hbuf, ash, adh, rowptr, recs, b1, obuf, n);
    // layer 2
    gemm_node<64><<<(n + 127) / 128, 256, 0, stream>>>(obuf, W2, as2, ad2, hbuf, ash, adh, n);
    gat_aggregate<1><<<(n + 3) / 4, 256, 0, stream>>>(hbuf, ash, adh, rowptr, recs, b2, obuf, n);
    // classifier
    mlp_kernel<<<(n + 7) / 8, 256, 0, stream>>>(obuf, Wc1, bc1, Wc2, bc2, (float*)d_out, n);
}

// Round 6
// 575.028 us; speedup vs baseline: 1.0530x; 1.0530x over previous
//
#include <hip/hip_runtime.h>
#include <hip/hip_bf16.h>
#include <hip/hip_fp16.h>

#define NEG_SLOPE 0.2f

__device__ __forceinline__ float leaky(float a) { return a > 0.f ? a : NEG_SLOPE * a; }

// ---------------- wvec: wv[0..15] = We1 @ ae1, wv[16..31] = We2 @ ae2 ----------------
__global__ void compute_wvec(const float* __restrict__ We1, const float* __restrict__ ae1,
                             const float* __restrict__ We2, const float* __restrict__ ae2,
                             float* __restrict__ wv) {
    int t = threadIdx.x;
    if (t < 16) {
        float s = 0.f;
        for (int k = 0; k < 64; ++k) s += We1[t * 64 + k] * ae1[k];
        wv[t] = s;
    } else if (t < 32) {
        int f = t - 16;
        float s = 0.f;
        for (int k = 0; k < 64; ++k) s += We2[f * 64 + k] * ae2[k];
        wv[16 + f] = s;
    }
}

// ---------------- pack: payload (ea1:f16|ea2:f16) + degree count + within-node rank ----------------
__global__ void pack_edges(const int* __restrict__ dst, const float* __restrict__ eattr,
                           const float* __restrict__ wv, int* __restrict__ deg,
                           uint2* __restrict__ meta, int E) {
    __shared__ float w1s[16], w2s[16];
    if (threadIdx.x < 16) w1s[threadIdx.x] = wv[threadIdx.x];
    else if (threadIdx.x < 32) w2s[threadIdx.x - 16] = wv[threadIdx.x];
    __syncthreads();
    int e = blockIdx.x * blockDim.x + threadIdx.x;
    if (e >= E) return;
    const float4* ep = (const float4*)(eattr + (size_t)e * 16);
    float4 q0 = ep[0], q1 = ep[1], q2 = ep[2], q3 = ep[3];
    float a[16] = {q0.x, q0.y, q0.z, q0.w, q1.x, q1.y, q1.z, q1.w,
                   q2.x, q2.y, q2.z, q2.w, q3.x, q3.y, q3.z, q3.w};
    float s1 = 0.f, s2 = 0.f;
#pragma unroll
    for (int f = 0; f < 16; ++f) { s1 += a[f] * w1s[f]; s2 += a[f] * w2s[f]; }
    unsigned int p1 = (unsigned int)__half_as_ushort(__float2half_rn(s1));
    unsigned int p2 = (unsigned int)__half_as_ushort(__float2half_rn(s2));
    int rank = atomicAdd(&deg[dst[e]], 1);  // degree count; old value = within-node rank
    meta[e] = make_uint2(p1 | (p2 << 16), (unsigned int)rank);
}

// ---------------- 3-kernel exclusive scan: deg -> rowptr ----------------
__global__ void scan_blocks(const int* __restrict__ deg, int* __restrict__ rowptr,
                            int* __restrict__ bsum, int n) {
    __shared__ int sh[1024];
    int i = blockIdx.x * 1024 + threadIdx.x;
    sh[threadIdx.x] = (i < n) ? deg[i] : 0;
    __syncthreads();
    for (int off = 1; off < 1024; off <<= 1) {
        int t = (threadIdx.x >= off) ? sh[threadIdx.x - off] : 0;
        __syncthreads();
        sh[threadIdx.x] += t;
        __syncthreads();
    }
    if (i < n) rowptr[i + 1] = sh[threadIdx.x];  // inclusive, pre-offset
    if (threadIdx.x == 1023) bsum[blockIdx.x] = sh[1023];
}

__global__ void scan_sums(int* __restrict__ bsum, int nb) {
    if (blockIdx.x == 0 && threadIdx.x == 0) {
        int run = 0;
        for (int b = 0; b < nb; ++b) { int t = bsum[b]; bsum[b] = run; run += t; }
    }
}

__global__ void scan_finalize(int* __restrict__ rowptr, const int* __restrict__ bsum, int n) {
    int i = blockIdx.x * blockDim.x + threadIdx.x;
    if (i < n) rowptr[i + 1] += bsum[i >> 10];
    if (i == 0) rowptr[0] = 0;
}

// ---------------- route: atomic-free XCD-local CSR scatter ----------------
// pos = rowptr[dst] + rank (rank captured during pack's degree atomic).
// Workgroup w handles only dst-slice (w&7): with round-robin blockIdx->XCD
// dispatch each recs slice is written by one XCD (write locality heuristic;
// correct under any mapping).
__global__ __launch_bounds__(256) void route_edges(
    const int* __restrict__ src, const int* __restrict__ dst,
    const uint2* __restrict__ meta, const int* __restrict__ rowptr,
    uint2* __restrict__ recs, int E, int slice_sz) {
    int xcd = blockIdx.x & 7;
    int team = blockIdx.x >> 3;
    int teams = gridDim.x >> 3;
    int lo = xcd * slice_sz, hi = lo + slice_sz;
    for (int e = team * 256 + threadIdx.x; e < E; e += teams * 256) {
        int d = dst[e];
        if (d < lo || d >= hi) continue;
        uint2 m = meta[e];
        int pos = rowptr[d] + (int)m.y;
        recs[pos] = make_uint2((unsigned int)src[e], m.x);
    }
}

// ---------------- node GEMM: h = X@W (K x 64) -> f16 rows, plus ash/adh (f32) ----------------
// Register-tiled: block = 128 rows x 64 cols, 256 threads, thread = 4 rows x 8 cols.
// h is written ONLY as f16 (consumed exclusively by the gather in gat_aggregate).
template <int K>
__global__ __launch_bounds__(256) void gemm_node(const float* __restrict__ X,
                                                 const float* __restrict__ W,
                                                 const float* __restrict__ a_s,
                                                 const float* __restrict__ a_d,
                                                 __half* __restrict__ Hout16,
                                                 float* __restrict__ ash,
                                                 float* __restrict__ adh, int n) {
    constexpr int KC = 64;
    __shared__ float xs[128 * 65];
    __shared__ float ws[KC * 64];
    int tid = threadIdx.x;
    int base = blockIdx.x * 128;
    int ct = tid & 7;   // cols ct*8 .. ct*8+7
    int rt = tid >> 3;  // rows rt*4 .. rt*4+3

    float acc[4][8];
#pragma unroll
    for (int i = 0; i < 4; ++i)
#pragma unroll
        for (int j = 0; j < 8; ++j) acc[i][j] = 0.f;

    for (int kc = 0; kc < K; kc += KC) {
#pragma unroll
        for (int p = 0; p < 8; ++p) {
            int idx = p * 256 + tid;  // 2048 float4s
            int row = idx >> 4;
            int f4 = idx & 15;
            float4 q = make_float4(0.f, 0.f, 0.f, 0.f);
            if (base + row < n) q = *(const float4*)(X + (size_t)(base + row) * K + kc + f4 * 4);
            float* dp = xs + row * 65 + f4 * 4;
            dp[0] = q.x; dp[1] = q.y; dp[2] = q.z; dp[3] = q.w;
        }
#pragma unroll
        for (int p = 0; p < 4; ++p) {
            int idx = p * 256 + tid;  // 1024 float4s
            int f = idx >> 4;
            int c4 = idx & 15;
            *(float4*)(ws + f * 64 + c4 * 4) =
                *(const float4*)(W + (size_t)(kc + f) * 64 + c4 * 4);
        }
        __syncthreads();
#pragma unroll 4
        for (int f = 0; f < KC; ++f) {
            float4 w0 = *(const float4*)(ws + f * 64 + ct * 8);
            float4 w1 = *(const float4*)(ws + f * 64 + ct * 8 + 4);
            float b0[8] = {w0.x, w0.y, w0.z, w0.w, w1.x, w1.y, w1.z, w1.w};
#pragma unroll
            for (int i = 0; i < 4; ++i) {
                float a = xs[(rt * 4 + i) * 65 + f];
#pragma unroll
                for (int j = 0; j < 8; ++j) acc[i][j] = fmaf(a, b0[j], acc[i][j]);
            }
        }
        __syncthreads();
    }

    float as_r[8], ad_r[8];
#pragma unroll
    for (int j = 0; j < 8; ++j) { as_r[j] = a_s[ct * 8 + j]; ad_r[j] = a_d[ct * 8 + j]; }
#pragma unroll
    for (int i = 0; i < 4; ++i) {
        int r = base + rt * 4 + i;
        float ps = 0.f, pd = 0.f;
#pragma unroll
        for (int j = 0; j < 8; ++j) {
            ps = fmaf(acc[i][j], as_r[j], ps);
            pd = fmaf(acc[i][j], ad_r[j], pd);
        }
        ps += __shfl_xor(ps, 1); pd += __shfl_xor(pd, 1);
        ps += __shfl_xor(ps, 2); pd += __shfl_xor(pd, 2);
        ps += __shfl_xor(ps, 4); pd += __shfl_xor(pd, 4);
        if (r < n) {
            union { __half h[8]; uint4 u; } pk;
#pragma unroll
            for (int j = 0; j < 8; ++j) pk.h[j] = __float2half_rn(acc[i][j]);
            *(uint4*)(Hout16 + (size_t)r * 64 + ct * 8) = pk.u;
            if (ct == 0) { ash[r] = ps; adh[r] = pd; }
        }
    }
}

// ---------------- GAT aggregation: one wave per destination node ----------------
// f16 value rows (128B gather per edge); alpha path stays f32.
template <int LAYER>
__global__ __launch_bounds__(256) void gat_aggregate(
    const __half* __restrict__ Hf, const float* __restrict__ ash, const float* __restrict__ adh,
    const int* __restrict__ rowptr, const uint2* __restrict__ recs,
    const float* __restrict__ bias, float* __restrict__ outp, int n) {
    int wave = threadIdx.x >> 6;
    int lane = threadIdx.x & 63;
    int i = blockIdx.x * 4 + wave;
    if (i >= n) return;
    int start = rowptr[i], end = rowptr[i + 1];
    float adi = adh[i];

    auto gete = [](unsigned int y) -> float {
        unsigned short u = (LAYER == 0) ? (unsigned short)(y & 0xffffu) : (unsigned short)(y >> 16);
        return __half2float(__ushort_as_half(u));
    };

    float acc = 0.f, z = 0.f, sea = 0.f;
    int j = start;
    for (; j + 4 <= end; j += 4) {
        uint2 r0 = recs[j], r1 = recs[j + 1], r2 = recs[j + 2], r3 = recs[j + 3];
        int s0 = (int)r0.x, s1 = (int)r1.x, s2 = (int)r2.x, s3 = (int)r3.x;
        float e0 = gete(r0.y), e1 = gete(r1.y), e2 = gete(r2.y), e3 = gete(r3.y);
        float a0 = ash[s0], a1 = ash[s1], a2 = ash[s2], a3 = ash[s3];
        float v0 = __half2float(Hf[(size_t)s0 * 64 + lane]);
        float v1 = __half2float(Hf[(size_t)s1 * 64 + lane]);
        float v2 = __half2float(Hf[(size_t)s2 * 64 + lane]);
        float v3 = __half2float(Hf[(size_t)s3 * 64 + lane]);
        float p0 = __expf(leaky(a0 + adi + e0));
        float p1 = __expf(leaky(a1 + adi + e1));
        float p2 = __expf(leaky(a2 + adi + e2));
        float p3 = __expf(leaky(a3 + adi + e3));
        acc = fmaf(p0, v0, acc);
        acc = fmaf(p1, v1, acc);
        acc = fmaf(p2, v2, acc);
        acc = fmaf(p3, v3, acc);
        z += (p0 + p1) + (p2 + p3);
        sea += (e0 + e1) + (e2 + e3);
    }
    for (; j < end; ++j) {
        uint2 r = recs[j];
        int s = (int)r.x;
        float e = gete(r.y);
        float v = __half2float(Hf[(size_t)s * 64 + lane]);
        float p = __expf(leaky(ash[s] + adi + e));
        acc = fmaf(p, v, acc);
        z += p;
        sea += e;
    }

    int d = end - start;
    float loop_sc = sea / (float)max(d, 1);
    float aself = leaky(ash[i] + adi + loop_sc);
    float pself = __expf(aself);
    z += pself;
    acc = fmaf(pself, __half2float(Hf[(size_t)i * 64 + lane]), acc);
    float o = acc / z + bias[lane];
    outp[(size_t)i * 64 + lane] = fmaxf(o, 0.f);  // both GAT layers are ReLU'd
}

// ---------------- classifier MLP: relu(X@Wc1+bc1)@Wc2+bc2 ----------------
__global__ __launch_bounds__(256) void mlp_kernel(const float* __restrict__ X,
                                                  const float* __restrict__ Wc1,
                                                  const float* __restrict__ bc1,
                                                  const float* __restrict__ Wc2,
                                                  const float* __restrict__ bc2,
                                                  float* __restrict__ outp, int n) {
    __shared__ float v[8 * 64];
    __shared__ float tb[8 * 32];
    int base = blockIdx.x * 8;
    for (int t = threadIdx.x; t < 512; t += 256) {
        int r = t >> 6;
        v[t] = (base + r < n) ? X[(size_t)base * 64 + t] : 0.f;
    }
    __syncthreads();
    int r = threadIdx.x >> 5, j = threadIdx.x & 31;
    float acc = bc1[j];
#pragma unroll
    for (int k = 0; k < 64; ++k) acc += v[r * 64 + k] * Wc1[k * 32 + j];
    acc = fmaxf(acc, 0.f);
    tb[r * 32 + j] = acc;
    __syncthreads();
    float lg = bc2[j];
#pragma unroll
    for (int k2 = 0; k2 < 32; ++k2) lg += tb[r * 32 + k2] * Wc2[k2 * 32 + j];
    int row = base + r;
    if (row < n) outp[(size_t)row * 32 + j] = lg;
}

extern "C" void kernel_launch(void* const* d_in, const int* in_sizes, int n_in,
                              void* d_out, int out_size, void* d_ws, size_t ws_size,
                              hipStream_t stream) {
    const float* x    = (const float*)d_in[0];
    const int*   ei   = (const int*)d_in[1];
    const float* eatt = (const float*)d_in[2];
    const float* W1   = (const float*)d_in[3];
    const float* as1  = (const float*)d_in[4];
    const float* ad1  = (const float*)d_in[5];
    const float* We1  = (const float*)d_in[6];
    const float* ae1  = (const float*)d_in[7];
    const float* b1   = (const float*)d_in[8];
    const float* W2   = (const float*)d_in[9];
    const float* as2  = (const float*)d_in[10];
    const float* ad2  = (const float*)d_in[11];
    const float* We2  = (const float*)d_in[12];
    const float* ae2  = (const float*)d_in[13];
    const float* b2   = (const float*)d_in[14];
    const float* Wc1  = (const float*)d_in[15];
    const float* bc1  = (const float*)d_in[16];
    const float* Wc2  = (const float*)d_in[17];
    const float* bc2  = (const float*)d_in[18];

    int n = in_sizes[0] / 128;
    int E = in_sizes[1] / 2;
    const int* src = ei;
    const int* dst = ei + E;

    // workspace carve (256B aligned)
    char* w = (char*)d_ws;
    auto alloc = [&](size_t bytes) { void* p = (void*)w; w += (bytes + 255) & ~(size_t)255; return p; };
    int* rowptr  = (int*)alloc((size_t)(n + 1) * 4);
    int* deg     = (int*)alloc((size_t)n * 4);
    int nb = (n + 1023) / 1024;
    int* bsum    = (int*)alloc((size_t)nb * 4);
    uint2* recs  = (uint2*)alloc((size_t)E * 8);
    uint2* meta  = (uint2*)alloc((size_t)E * 8);
    float* wv    = (float*)alloc(32 * 4);
    __half* hbuf16 = (__half*)alloc((size_t)n * 64 * 2);
    float* obuf  = (float*)alloc((size_t)n * 64 * 4);
    float* ash   = (float*)alloc((size_t)n * 4);
    float* adh   = (float*)alloc((size_t)n * 4);

    int slice_sz = (n + 7) / 8;

    hipMemsetAsync(deg, 0, (size_t)n * 4, stream);
    compute_wvec<<<1, 64, 0, stream>>>(We1, ae1, We2, ae2, wv);
    pack_edges<<<(E + 255) / 256, 256, 0, stream>>>(dst, eatt, wv, deg, meta, E);
    scan_blocks<<<nb, 1024, 0, stream>>>(deg, rowptr, bsum, n);
    scan_sums<<<1, 64, 0, stream>>>(bsum, nb);
    scan_finalize<<<(n + 255) / 256, 256, 0, stream>>>(rowptr, bsum, n);
    route_edges<<<1024, 256, 0, stream>>>(src, dst, meta, rowptr, recs, E, slice_sz);

    // layer 1
    gemm_node<128><<<(n + 127) / 128, 256, 0, stream>>>(x, W1, as1, ad1, hbuf16, ash, adh, n);
    gat_aggregate<0><<<(n + 3) / 4, 256, 0, stream>>>(hbuf16, ash, adh, rowptr, recs, b1, obuf, n);
    // layer 2
    gemm_node<64><<<(n + 127) / 128, 256, 0, stream>>>(obuf, W2, as2, ad2, hbuf16, ash, adh, n);
    gat_aggregate<1><<<(n + 3) / 4, 256, 0, stream>>>(hbuf16, ash, adh, rowptr, recs, b2, obuf, n);
    // classifier
    mlp_kernel<<<(n + 7) / 8, 256, 0, stream>>>(obuf, Wc1, bc1, Wc2, bc2, (float*)d_out, n);
}